// Round 12
// baseline (464.440 us; speedup 1.0000x reference)
//
#include <hip/hip_runtime.h>
#include <stdint.h>

#define NN 50000
#define NE 800000
#define CH 128

// ---------------- threefry2x32 (exact JAX semantics) ----------------
__host__ __device__ inline void tf2x32(uint32_t k0, uint32_t k1, uint32_t& x0, uint32_t& x1) {
  uint32_t ks2 = k0 ^ k1 ^ 0x1BD11BDAu;
  x0 += k0; x1 += k1;
#define ROTL(v, r) (((v) << (r)) | ((v) >> (32 - (r))))
#define RND(r) { x0 += x1; x1 = ROTL(x1, r); x1 ^= x0; }
  RND(13) RND(15) RND(26) RND(6)
  x0 += k1; x1 += ks2 + 1u;
  RND(17) RND(29) RND(16) RND(24)
  x0 += ks2; x1 += k0 + 2u;
  RND(13) RND(15) RND(26) RND(6)
  x0 += k0; x1 += k1 + 3u;
  RND(17) RND(29) RND(16) RND(24)
  x0 += k1; x1 += ks2 + 4u;
  RND(13) RND(15) RND(26) RND(6)
  x0 += ks2; x1 += k0 + 5u;
#undef RND
#undef ROTL
}

__device__ inline float bits_to_u(uint32_t b) {
  float f = __uint_as_float(0x3F800000u | (b >> 9)) - 1.0f;  // [0,1)
  f = f + 1e-10f;
  return fmaxf(1e-10f, f);
}

// ---------------- graph preprocessing ----------------
__global__ __launch_bounds__(256) void deg_k(const int* __restrict__ dst, int* __restrict__ degi) {
  int i = blockIdx.x * 256 + threadIdx.x;
  if (i < NE) atomicAdd(&degi[dst[i]], 1);
}

// scan over degrees; also emits dinv
__global__ __launch_bounds__(256) void scan1_k(const int* __restrict__ degi, int* __restrict__ offs,
                                               int* __restrict__ part, float* __restrict__ dinv) {
  __shared__ int tmp[256];
  int t = threadIdx.x, b = blockIdx.x, i = b * 256 + t;
  int v = (i < NN) ? degi[i] : 0;
  tmp[t] = v;
  __syncthreads();
  for (int s = 1; s < 256; s <<= 1) {
    int a = (t >= s) ? tmp[t - s] : 0;
    __syncthreads();
    tmp[t] += a;
    __syncthreads();
  }
  int incl = tmp[t];
  if (i < NN) {
    offs[i] = incl - v;
    dinv[i] = 1.0f / sqrtf((float)(v + 1));
  }
  if (t == 255) part[b] = incl;
}

__global__ void scan2_k(int* part, int nparts) {
  if (threadIdx.x == 0 && blockIdx.x == 0) {
    int run = 0;
    for (int i = 0; i < nparts; ++i) { int v = part[i]; part[i] = run; run += v; }
  }
}

__global__ __launch_bounds__(256) void scan3_k(int* __restrict__ offs, const int* __restrict__ part) {
  int i = blockIdx.x * 256 + threadIdx.x;
  if (i < NN) offs[i] += part[blockIdx.x];
  if (i == 0) offs[NN] = NE;
}

// scatter edges into dst-buckets; srcs only (norm computed on the fly in agg).
__global__ __launch_bounds__(256) void place_k(const int* __restrict__ src, const int* __restrict__ dst,
                                               const int* __restrict__ offs,
                                               int* __restrict__ cnt, int* __restrict__ srcs) {
  int i = blockIdx.x * 256 + threadIdx.x;
  if (i < NE) {
    int d = dst[i];
    int p = offs[d] + atomicAdd(&cnt[d], 1);
    srcs[p] = src[i];
  }
}

// ---------------- gumbel precompute (+ fused eout init to 3.0) ----------------
__global__ __launch_bounds__(256) void gum_k(float* __restrict__ gum, float* __restrict__ eout,
                                             uint32_t k00, uint32_t k01, uint32_t k10, uint32_t k11,
                                             uint32_t k20, uint32_t k21) {
  int i = blockIdx.x * 256 + threadIdx.x;
  if (i >= 3 * NN) return;
  if (i < NN) eout[i] = 3.0f;
  int l = i / NN;
  int n = i - l * NN;
  uint32_t kx, ky;
  if (l == 0) { kx = k00; ky = k01; }
  else if (l == 1) { kx = k10; ky = k11; }
  else { kx = k20; ky = k21; }
  int j0 = 2 * n, j1 = 2 * n + 1;
  uint32_t w0, w1;
  if (j0 < NN) {
    uint32_t a0 = (uint32_t)j0, a1 = (uint32_t)(j0 + NN);
    tf2x32(kx, ky, a0, a1); w0 = a0;
    uint32_t b0 = (uint32_t)j1, b1 = (uint32_t)(j1 + NN);
    tf2x32(kx, ky, b0, b1); w1 = b0;
  } else {
    uint32_t a0 = (uint32_t)(j0 - NN), a1 = (uint32_t)j0;
    tf2x32(kx, ky, a0, a1); w0 = a1;
    uint32_t b0 = (uint32_t)(j1 - NN), b1 = (uint32_t)j1;
    tf2x32(kx, ky, b0, b1); w1 = b1;
  }
  float u0 = bits_to_u(w0), u1 = bits_to_u(w1);
  gum[2 * (size_t)i]     = -logf(-logf(u0));
  gum[2 * (size_t)i + 1] = -logf(-logf(u1));
}

// ---------------- h = x @ W  (f32, 64x128 tile, BK=32, float4 both operands) ----------------
__global__ __launch_bounds__(256) void lin_k(const float* __restrict__ x, const float* __restrict__ W,
                                             float* __restrict__ h) {
  __shared__ float Ws[32 * 128];    // [k][c]
  __shared__ float xs[64][36];      // [row][k], padded
  int t = threadIdx.x;
  int row0 = blockIdx.x << 6;
  int tr = t & 15, tc = t >> 4;     // rows tr+16i, col4s tc and 16+tc
  float4 acc[4][2];
#pragma unroll
  for (int i = 0; i < 4; ++i) { acc[i][0] = make_float4(0,0,0,0); acc[i][1] = make_float4(0,0,0,0); }

  for (int kt = 0; kt < 4; ++kt) {
    __syncthreads();
    {
      const float4* W4 = (const float4*)(W + (size_t)(kt * 32) * 128);
      float4* Ws4 = (float4*)Ws;
#pragma unroll
      for (int i = 0; i < 4; ++i) Ws4[t + 256 * i] = W4[t + 256 * i];
    }
    {
#pragma unroll
      for (int i = 0; i < 2; ++i) {
        int f = t + 256 * i;            // 0..511
        int row = f >> 3, c4 = f & 7;
        int gr = row0 + row;
        float4 v = make_float4(0,0,0,0);
        if (gr < NN) v = ((const float4*)x)[(size_t)gr * 32 + kt * 8 + c4];
        *(float4*)&xs[row][4 * c4] = v;
      }
    }
    __syncthreads();
    const float4* Ws4 = (const float4*)Ws;
#pragma unroll
    for (int kk = 0; kk < 32; kk += 4) {
      float4 xv[4];
#pragma unroll
      for (int i = 0; i < 4; ++i) xv[i] = *(const float4*)&xs[tr + 16 * i][kk];
#pragma unroll
      for (int d = 0; d < 4; ++d) {
        float4 w0 = Ws4[(kk + d) * 32 + tc];
        float4 w1 = Ws4[(kk + d) * 32 + 16 + tc];
#pragma unroll
        for (int i = 0; i < 4; ++i) {
          float xd = ((const float*)&xv[i])[d];
          acc[i][0].x += xd * w0.x; acc[i][0].y += xd * w0.y;
          acc[i][0].z += xd * w0.z; acc[i][0].w += xd * w0.w;
          acc[i][1].x += xd * w1.x; acc[i][1].y += xd * w1.y;
          acc[i][1].z += xd * w1.z; acc[i][1].w += xd * w1.w;
        }
      }
    }
  }
#pragma unroll
  for (int i = 0; i < 4; ++i) {
    int gr = row0 + tr + 16 * i;
    if (gr < NN) {
      ((float4*)h)[(size_t)gr * 32 + tc] = acc[i][0];
      ((float4*)h)[(size_t)gr * 32 + 16 + tc] = acc[i][1];
    }
  }
}

// ---------------- aggregate + bias (+ GELU) + FUSED decide ----------------
__device__ inline float gelu_exact(float v) {
  return 0.5f * v * (1.0f + erff(v / 1.4142135623730951f));
}

// wave per node; gather identical to r11 (passing). Epilogue: Q row -> 512B LDS strip,
// then 64-lane MLP (lane = hidden unit), f64 4-chain (reassoc-safe), butterfly logits,
// gumbel compare, write eout/z. MODE 0/1/2 as in old decide_k.
template <int MODE>
__global__ __launch_bounds__(256) void agg_k(const float* __restrict__ h, const float* __restrict__ dinv,
                                             const int* __restrict__ offs, const int* __restrict__ srcs,
                                             const float* __restrict__ bias,
                                             const float* __restrict__ W1, const float* __restrict__ b1,
                                             const float* __restrict__ W2, const float* __restrict__ b2,
                                             const float* __restrict__ gum,
                                             float* __restrict__ xout, float* __restrict__ zout,
                                             float* __restrict__ eout) {
  __shared__ float xrow[4][128];
  int lane = threadIdx.x & 63, w = threadIdx.x >> 6;
  int n = blockIdx.x * 4 + w;
  if (n >= NN) return;
  int c4 = lane & 31, hh = lane >> 5;
  int s0 = offs[n], s1 = offs[n + 1];
  float dv = dinv[n];
  double a0 = 0.0, a1 = 0.0, a2 = 0.0, a3 = 0.0;
  for (int p0 = s0; p0 < s1; p0 += 64) {
    int m = s1 - p0; if (m > 64) m = 64;
    int sv = 0; float nv = 0.f;
    if (lane < m) {
      sv = __builtin_nontemporal_load(&srcs[p0 + lane]);
      nv = dinv[sv] * dv;   // f32 product, identical to ref's norm
    }
    int i = 0;
    for (; i + 8 <= m; i += 8) {
      int   sA = __shfl(sv, i + hh),     sB = __shfl(sv, i + 2 + hh);
      int   sC = __shfl(sv, i + 4 + hh), sD = __shfl(sv, i + 6 + hh);
      float nA = __shfl(nv, i + hh),     nB = __shfl(nv, i + 2 + hh);
      float nC = __shfl(nv, i + 4 + hh), nD = __shfl(nv, i + 6 + hh);
      float4 hA = *(const float4*)&h[(size_t)sA * CH + 4 * c4];
      float4 hB = *(const float4*)&h[(size_t)sB * CH + 4 * c4];
      float4 hC = *(const float4*)&h[(size_t)sC * CH + 4 * c4];
      float4 hD = *(const float4*)&h[(size_t)sD * CH + 4 * c4];
      a0 += (double)(hA.x * nA); a1 += (double)(hA.y * nA); a2 += (double)(hA.z * nA); a3 += (double)(hA.w * nA);
      a0 += (double)(hB.x * nB); a1 += (double)(hB.y * nB); a2 += (double)(hB.z * nB); a3 += (double)(hB.w * nB);
      a0 += (double)(hC.x * nC); a1 += (double)(hC.y * nC); a2 += (double)(hC.z * nC); a3 += (double)(hC.w * nC);
      a0 += (double)(hD.x * nD); a1 += (double)(hD.y * nD); a2 += (double)(hD.z * nD); a3 += (double)(hD.w * nD);
    }
    for (; i < m; i += 2) {
      int   s = __shfl(sv, i + hh);
      float nm = __shfl(nv, i + hh);
      float4 hv = *(const float4*)&h[(size_t)s * CH + 4 * c4];
      a0 += (double)(hv.x * nm); a1 += (double)(hv.y * nm); a2 += (double)(hv.z * nm); a3 += (double)(hv.w * nm);
    }
  }
  a0 += __shfl_xor(a0, 32); a1 += __shfl_xor(a1, 32);
  a2 += __shfl_xor(a2, 32); a3 += __shfl_xor(a3, 32);
  if (hh == 0) {
    float selfn = dv * dv;  // self-loop appended last, like ref
    float4 hn = *(const float4*)&h[(size_t)n * CH + 4 * c4];
    a0 += (double)(hn.x * selfn); a1 += (double)(hn.y * selfn);
    a2 += (double)(hn.z * selfn); a3 += (double)(hn.w * selfn);
    float4 bv = *(const float4*)&bias[4 * c4];
    float r0 = (float)a0 + bv.x;
    float r1 = (float)a1 + bv.y;
    float r2 = (float)a2 + bv.z;
    float r3 = (float)a3 + bv.w;
    if (MODE < 2) { r0 = gelu_exact(r0); r1 = gelu_exact(r1); r2 = gelu_exact(r2); r3 = gelu_exact(r3); }
    float4 o; o.x = r0; o.y = r1; o.z = r2; o.w = r3;
    *(float4*)&xout[(size_t)n * CH + 4 * c4] = o;
    *(float4*)&xrow[w][4 * c4] = o;       // stage for fused decide (wave-local LDS)
  }

  // ---- fused decide (verified decision algebra; f64 4-chain hidden dot) ----
  float ev = 3.0f;
  if (MODE > 0) ev = eout[n];             // uniform load (broadcast)
  bool doDec = (MODE == 0) || (ev == 3.0f);
  if (!doDec) return;                     // wave-uniform

  // lane = hidden unit j; 4 interleaved f64 chains over k (reassociation-safe)
  double c0 = 0.0, c1 = 0.0, c2 = 0.0, c3 = 0.0;
  const float* xr = xrow[w];
#pragma unroll 8
  for (int k = 0; k < 128; k += 4) {
    c0 += (double)xr[k]     * (double)W1[(size_t)(k)     * 64 + lane];
    c1 += (double)xr[k + 1] * (double)W1[(size_t)(k + 1) * 64 + lane];
    c2 += (double)xr[k + 2] * (double)W1[(size_t)(k + 2) * 64 + lane];
    c3 += (double)xr[k + 3] * (double)W1[(size_t)(k + 3) * 64 + lane];
  }
  double accd = (c0 + c1) + (c2 + c3);
  float hid = fmaxf((float)accd + b1[lane], 0.0f);
  double p0 = (double)hid * (double)W2[2 * lane];
  double p1 = (double)hid * (double)W2[2 * lane + 1];
#pragma unroll
  for (int off = 32; off >= 1; off >>= 1) {
    p0 += __shfl_xor(p0, off);
    p1 += __shfl_xor(p1, off);
  }
  float gg0 = gum[2 * (size_t)n];
  float gg1 = gum[2 * (size_t)n + 1];
  float l0 = (float)p0 + b2[0];
  float l1 = (float)p1 + b2[1];
  bool ex = (l1 + gg1) > (l0 + gg0);      // wave-uniform result

  if (ex && lane == 0) eout[n] = (float)MODE;
  if (MODE == 2 || ex) {
    float2 v;
    v.x = xr[2 * lane];
    v.y = xr[2 * lane + 1];
    *(float2*)&zout[(size_t)n * CH + 2 * lane] = v;
  }
}

// single-block count of active[] from eout; no atomics
__global__ __launch_bounds__(1024) void cnt_k(const float* __restrict__ eout, float* __restrict__ aout) {
  __shared__ int s1[16], s2[16];
  int t = threadIdx.x;
  int c1 = 0, c2 = 0;
  for (int i = t; i < NN / 4; i += 1024) {
    float4 v = ((const float4*)eout)[i];
    c1 += (v.x < 0.5f) + (v.y < 0.5f) + (v.z < 0.5f) + (v.w < 0.5f);
    c2 += (v.x < 1.5f) + (v.y < 1.5f) + (v.z < 1.5f) + (v.w < 1.5f);
  }
#pragma unroll
  for (int off = 32; off >= 1; off >>= 1) { c1 += __shfl_xor(c1, off); c2 += __shfl_xor(c2, off); }
  if ((t & 63) == 0) { s1[t >> 6] = c1; s2[t >> 6] = c2; }
  __syncthreads();
  if (t == 0) {
    int a1 = 0, a2 = 0;
#pragma unroll
    for (int i = 0; i < 16; ++i) { a1 += s1[i]; a2 += s2[i]; }
    aout[0] = 50000.0f;
    aout[1] = (float)(NN - a1);
    aout[2] = (float)(NN - a2);
  }
}

// ---------------- host ----------------
extern "C" void kernel_launch(void* const* d_in, const int* in_sizes, int n_in,
                              void* d_out, int out_size, void* d_ws, size_t ws_size,
                              hipStream_t stream) {
  const float* x_in = (const float*)d_in[0];
  const int* eidx = (const int*)d_in[1];
  const int* esrc = eidx;
  const int* edst = eidx + NE;
  const float* convw[3] = {(const float*)d_in[2], (const float*)d_in[4], (const float*)d_in[6]};
  const float* convb[3] = {(const float*)d_in[3], (const float*)d_in[5], (const float*)d_in[7]};
  const float* cw1 = (const float*)d_in[8];
  const float* cb1 = (const float*)d_in[9];
  const float* cw2 = (const float*)d_in[10];
  const float* cb2 = (const float*)d_in[11];
  // d_in[12] = temp_w: unused (temperature > 0 cancels in the argmax)

  float* out = (float*)d_out;
  float* zout = out;
  float* eout = out + (size_t)NN * CH;
  float* aout = eout + NN;

  char* w = (char*)d_ws;
  float* P = (float*)w;   w += (size_t)NN * CH * 4;
  float* Q = (float*)w;   w += (size_t)NN * CH * 4;
  int* srcs = (int*)w;    w += (size_t)NE * 4;
  float* gum = (float*)w; w += (size_t)3 * NN * 2 * 4;
  int* offs = (int*)w;    w += (size_t)(NN + 1) * 4;
  float* dinv = (float*)w; w += (size_t)NN * 4;
  char* zr0 = w;
  int* degi = (int*)w;    w += (size_t)NN * 4;
  int* cnt = (int*)w;     w += (size_t)NN * 4;
  int* parts = (int*)w;   w += 1024;

  hipMemsetAsync(zr0, 0, (size_t)(2 * NN) * 4, stream);

  uint32_t key[3][2];
  for (int l = 0; l < 3; ++l) {
    uint32_t a = 0u, b = (uint32_t)l;
    tf2x32(0u, 42u, a, b);
    key[l][0] = a; key[l][1] = b;
  }

  const int nblkN = (NN + 255) / 256;
  deg_k<<<(NE + 255) / 256, 256, 0, stream>>>(edst, degi);
  scan1_k<<<nblkN, 256, 0, stream>>>(degi, offs, parts, dinv);
  scan2_k<<<1, 64, 0, stream>>>(parts, nblkN);
  scan3_k<<<nblkN, 256, 0, stream>>>(offs, parts);
  place_k<<<(NE + 255) / 256, 256, 0, stream>>>(esrc, edst, offs, cnt, srcs);
  gum_k<<<(3 * NN + 255) / 256, 256, 0, stream>>>(gum, eout, key[0][0], key[0][1], key[1][0], key[1][1],
                                                  key[2][0], key[2][1]);

  const int LB = (NN + 63) / 64;   // 782 blocks
  const int AB = (NN + 3) / 4;     // 12500 blocks
  lin_k<<<LB, 256, 0, stream>>>(x_in, convw[0], P);
  agg_k<0><<<AB, 256, 0, stream>>>(P, dinv, offs, srcs, convb[0], cw1, cb1, cw2, cb2,
                                   gum, Q, zout, eout);
  lin_k<<<LB, 256, 0, stream>>>(Q, convw[1], P);
  agg_k<1><<<AB, 256, 0, stream>>>(P, dinv, offs, srcs, convb[1], cw1, cb1, cw2, cb2,
                                   gum + (size_t)NN * 2, Q, zout, eout);
  lin_k<<<LB, 256, 0, stream>>>(Q, convw[2], P);
  agg_k<2><<<AB, 256, 0, stream>>>(P, dinv, offs, srcs, convb[2], cw1, cb1, cw2, cb2,
                                   gum + (size_t)2 * NN * 2, Q, zout, eout);
  cnt_k<<<1, 1024, 0, stream>>>(eout, aout);
}